// Round 19
// baseline (349.879 us; speedup 1.0000x reference)
//
#include <hip/hip_runtime.h>

typedef __attribute__((ext_vector_type(8))) __bf16 bf16x8;
typedef __attribute__((ext_vector_type(4))) float f32x4;

#define SLEN 1024
#define DMODEL 1024
#define NHEADS 16
#define DKH 64
#define BATCH 8

__device__ __forceinline__ unsigned short f2bf(float f) {
  unsigned u = __builtin_bit_cast(unsigned, f);
  u += 0x7FFFu + ((u >> 16) & 1u);
  return (unsigned short)(u >> 16);
}

__device__ __forceinline__ void gload_lds16(const void* g, void* l) {
  __builtin_amdgcn_global_load_lds((const __attribute__((address_space(1))) unsigned int*)g,
                                   (__attribute__((address_space(3))) unsigned int*)l, 16, 0, 0);
}

// ---------------- mask dtype detection: flag=1 -> byte mask, 0 -> int32 mask
__global__ void detect_mask(const unsigned char* __restrict__ m, int* __restrict__ flag) {
  int t = threadIdx.x;
  unsigned any = 0;
  for (int j = t; j < 4096; j += 64) any |= m[j * 4 + 1];
  unsigned long long b = __ballot(any != 0);
  if (t == 0) *flag = (b != 0) ? 1 : 0;
}

// ---------------- bit-pack mask: one block per (b,q) row of 1024 -> 32 words
__global__ __launch_bounds__(256) void mask_pack(const unsigned char* __restrict__ m,
                                                 const int* __restrict__ flagp,
                                                 unsigned* __restrict__ mb) {
  long base = (long)blockIdx.x << 10;
  int tid = threadIdx.x;
  int flag = *flagp;
  unsigned nib;
  if (flag) {
    uchar4 v = ((const uchar4*)(m + base))[tid];
    nib = (v.x ? 1u : 0u) | (v.y ? 2u : 0u) | (v.z ? 4u : 0u) | (v.w ? 8u : 0u);
  } else {
    int4 v = ((const int4*)((const int*)m + base))[tid];
    nib = (v.x ? 1u : 0u) | (v.y ? 2u : 0u) | (v.z ? 4u : 0u) | (v.w ? 8u : 0u);
  }
  __shared__ unsigned char nibs[256];
  nibs[tid] = (unsigned char)nib;
  __syncthreads();
  if (tid < 32) {
    unsigned wv = 0;
#pragma unroll
    for (int i = 0; i < 8; i++) wv |= ((unsigned)nibs[tid * 8 + i]) << (i * 4);
    mb[((long)blockIdx.x << 5) + tid] = wv;
  }
}

// ---------------- fp32 -> bf16 bulk convert, 7 tensors via blockIdx.y
__global__ __launch_bounds__(256) void cvt_all(
    const float* __restrict__ i0, const float* __restrict__ i1,
    const float* __restrict__ i2, const float* __restrict__ w0,
    const float* __restrict__ w1, const float* __restrict__ w2,
    const float* __restrict__ w3, unsigned short* __restrict__ xo0,
    unsigned short* __restrict__ xo1, unsigned short* __restrict__ xo2,
    unsigned short* __restrict__ wo0, unsigned short* __restrict__ wo1,
    unsigned short* __restrict__ wo2, unsigned short* __restrict__ wo3,
    int n8x, int n8w) {
  int which = blockIdx.y;
  const float* in;
  unsigned short* o;
  int n8;
  if (which < 3) {
    in = which == 0 ? i0 : which == 1 ? i1 : i2;
    o = which == 0 ? xo0 : which == 1 ? xo1 : xo2;
    n8 = n8x;
  } else {
    in = which == 3 ? w0 : which == 4 ? w1 : which == 5 ? w2 : w3;
    o = which == 3 ? wo0 : which == 4 ? wo1 : which == 5 ? wo2 : wo3;
    n8 = n8w;
  }
  int i = blockIdx.x * 256 + threadIdx.x;
  if (i >= n8) return;
  const float4* p = (const float4*)in;
  float4 f0 = p[2 * i], f1 = p[2 * i + 1];
  union { unsigned short us[8]; uint4 v; } pk;
  pk.us[0] = f2bf(f0.x); pk.us[1] = f2bf(f0.y); pk.us[2] = f2bf(f0.z); pk.us[3] = f2bf(f0.w);
  pk.us[4] = f2bf(f1.x); pk.us[5] = f2bf(f1.y); pk.us[6] = f2bf(f1.z); pk.us[7] = f2bf(f1.w);
  ((uint4*)o)[i] = pk.v;
}

// ---------------- merged QKV projection GEMM (z = 0/1/2 -> Q/K/V)
// bf16 NT, BK=64, XOR-swizzled LDS; z==2 writes V TRANSPOSED [z][d][s] (b64)
__global__ __launch_bounds__(256) void gemm_proj3(
    const unsigned short* __restrict__ A0, const unsigned short* __restrict__ A1,
    const unsigned short* __restrict__ A2, const unsigned short* __restrict__ B0,
    const unsigned short* __restrict__ B1, const unsigned short* __restrict__ B2,
    unsigned short* __restrict__ O0, unsigned short* __restrict__ O1,
    unsigned short* __restrict__ O2) {
  const int z = blockIdx.z;
  const unsigned short* Ab = z == 0 ? A0 : z == 1 ? A1 : A2;
  const unsigned short* Bb = z == 0 ? B0 : z == 1 ? B1 : B2;
  unsigned short* obf = z == 0 ? O0 : z == 1 ? O1 : O2;
  const float scale = z == 0 ? 0.125f : 1.0f;

  const int m0 = blockIdx.x * 128;
  const int n0 = blockIdx.y * 128;
  const int tid = threadIdx.x;
  const int l = tid & 63;
  const int w = tid >> 6;
  const int wr = w >> 1, wc = w & 1;
  const int rl = l & 15, hi = l >> 4;

  __shared__ __attribute__((aligned(16))) unsigned short As[128 * 64];
  __shared__ __attribute__((aligned(16))) unsigned short Bs[128 * 64];

  f32x4 acc[4][4];
#pragma unroll
  for (int i = 0; i < 4; i++)
#pragma unroll
    for (int j = 0; j < 4; j++) acc[i][j] = f32x4{0.f, 0.f, 0.f, 0.f};

  for (int k0 = 0; k0 < 1024; k0 += 64) {
    __syncthreads();
#pragma unroll
    for (int i = 0; i < 4; i++) {
      int o = (i * 256 + tid) * 16;
      int row = o >> 7, cb = o & 127;
      int cbs = cb ^ ((row & 7) << 4);
      gload_lds16(Ab + (long)(m0 + row) * 1024 + k0 + (cbs >> 1), (char*)As + o);
    }
#pragma unroll
    for (int i = 0; i < 4; i++) {
      int o = (i * 256 + tid) * 16;
      int row = o >> 7, cb = o & 127;
      int cbs = cb ^ ((row & 7) << 4);
      gload_lds16(Bb + (long)(n0 + row) * 1024 + k0 + (cbs >> 1), (char*)Bs + o);
    }
    __syncthreads();

#pragma unroll
    for (int ks = 0; ks < 2; ks++) {
      int kb = ks * 64 + hi * 16;
      bf16x8 af[4], bfr[4];
#pragma unroll
      for (int mi = 0; mi < 4; mi++) {
        int row = wr * 64 + mi * 16 + rl;
        af[mi] = *(const bf16x8*)((const char*)As + row * 128 + (kb ^ ((row & 7) << 4)));
      }
#pragma unroll
      for (int ni = 0; ni < 4; ni++) {
        int row = wc * 64 + ni * 16 + rl;
        bfr[ni] = *(const bf16x8*)((const char*)Bs + row * 128 + (kb ^ ((row & 7) << 4)));
      }
#pragma unroll
      for (int mi = 0; mi < 4; mi++)
#pragma unroll
        for (int ni = 0; ni < 4; ni++)
          acc[mi][ni] = __builtin_amdgcn_mfma_f32_16x16x32_bf16(af[mi], bfr[ni], acc[mi][ni], 0, 0, 0);
    }
  }

  const int r0 = hi << 2;
#pragma unroll
  for (int mi = 0; mi < 4; mi++) {
#pragma unroll
    for (int ni = 0; ni < 4; ni++) {
      f32x4 v = acc[mi][ni];
      int row = m0 + wr * 64 + mi * 16 + r0;
      int col = n0 + wc * 64 + ni * 16 + rl;
      if (z == 2) {
        union { unsigned short us[4]; unsigned long long vv; } pk;
        pk.us[0] = f2bf(v[0]); pk.us[1] = f2bf(v[1]);
        pk.us[2] = f2bf(v[2]); pk.us[3] = f2bf(v[3]);
        long idx = ((long)(((row >> 10) * 16 + (col >> 6)) * 64 + (col & 63)) << 10) + (row & 1023);
        *(unsigned long long*)&obf[idx] = pk.vv;
      } else {
#pragma unroll
        for (int j = 0; j < 4; j++) {
          int rr = row + j;
          long idx = (((long)((rr >> 10) * 16 + (col >> 6)) * 1024 + (rr & 1023)) << 6) + (col & 63);
          obf[idx] = f2bf(v[j] * scale);
        }
      }
    }
  }
}

// ---------------- fused FC + residual + LayerNorm
// BM=32, BN=1024 (full rows), 512 thr / 8 waves; wave w owns cols [w*128,+128).
// A (ctx) staged swizzled in LDS; B (Wfc, 2 MB) read direct from L2.
__global__ __launch_bounds__(512) void gemm_fc_ln(
    const unsigned short* __restrict__ ctx, const unsigned short* __restrict__ Wfc,
    const float* __restrict__ inQ, const float* __restrict__ gamma,
    const float* __restrict__ beta, float* __restrict__ out) {
  const int m0 = blockIdx.x * 32;
  const int tid = threadIdx.x;
  const int l = tid & 63, w = tid >> 6;
  const int rl = l & 15, hi = l >> 4;

  __shared__ __attribute__((aligned(16))) unsigned short As[32 * 64];  // 4 KB swz
  __shared__ float rsum[8][32], rsq[8][32];

  f32x4 acc[2][8];
#pragma unroll
  for (int i = 0; i < 2; i++)
#pragma unroll
    for (int j = 0; j < 8; j++) acc[i][j] = f32x4{0.f, 0.f, 0.f, 0.f};

  for (int k0 = 0; k0 < 1024; k0 += 64) {
    __syncthreads();
    if (tid < 256) {
      int o = tid * 16;
      int row = o >> 7, cb = o & 127;
      int cbs = cb ^ ((row & 7) << 4);
      gload_lds16(ctx + (long)(m0 + row) * 1024 + k0 + (cbs >> 1), (char*)As + o);
    }
    __syncthreads();

#pragma unroll
    for (int ks = 0; ks < 2; ks++) {
      int kb = ks * 64 + hi * 16;
      bf16x8 af[2];
#pragma unroll
      for (int mi = 0; mi < 2; mi++) {
        int row = mi * 16 + rl;
        af[mi] = *(const bf16x8*)((const char*)As + row * 128 + (kb ^ ((row & 7) << 4)));
      }
#pragma unroll
      for (int ni = 0; ni < 8; ni++) {
        int bn = w * 128 + ni * 16 + rl;
        bf16x8 bf = *(const bf16x8*)(Wfc + (long)bn * 1024 + k0 + ks * 32 + hi * 8);
#pragma unroll
        for (int mi = 0; mi < 2; mi++)
          acc[mi][ni] = __builtin_amdgcn_mfma_f32_16x16x32_bf16(af[mi], bf, acc[mi][ni], 0, 0, 0);
      }
    }
  }

  // residual add + per-thread row partials (rows mi*16+hi*4+j, cols w*128+ni*16+rl)
  float s[2][4], q2[2][4];
#pragma unroll
  for (int mi = 0; mi < 2; mi++)
#pragma unroll
    for (int j = 0; j < 4; j++) { s[mi][j] = 0.f; q2[mi][j] = 0.f; }
#pragma unroll
  for (int mi = 0; mi < 2; mi++) {
#pragma unroll
    for (int ni = 0; ni < 8; ni++) {
      int col = w * 128 + ni * 16 + rl;
#pragma unroll
      for (int j = 0; j < 4; j++) {
        int r = mi * 16 + hi * 4 + j;
        float x = acc[mi][ni][j] + inQ[(long)(m0 + r) * 1024 + col];
        acc[mi][ni][j] = x;
        s[mi][j] += x;
        q2[mi][j] += x * x;
      }
    }
  }
#pragma unroll
  for (int mi = 0; mi < 2; mi++)
#pragma unroll
    for (int j = 0; j < 4; j++) {
      s[mi][j] += __shfl_xor(s[mi][j], 1);  q2[mi][j] += __shfl_xor(q2[mi][j], 1);
      s[mi][j] += __shfl_xor(s[mi][j], 2);  q2[mi][j] += __shfl_xor(q2[mi][j], 2);
      s[mi][j] += __shfl_xor(s[mi][j], 4);  q2[mi][j] += __shfl_xor(q2[mi][j], 4);
      s[mi][j] += __shfl_xor(s[mi][j], 8);  q2[mi][j] += __shfl_xor(q2[mi][j], 8);
    }
  if (rl == 0) {
#pragma unroll
    for (int mi = 0; mi < 2; mi++)
#pragma unroll
      for (int j = 0; j < 4; j++) {
        int r = mi * 16 + hi * 4 + j;
        rsum[w][r] = s[mi][j];
        rsq[w][r] = q2[mi][j];
      }
  }
  __syncthreads();
  float mu[2][4], rstd[2][4];
#pragma unroll
  for (int mi = 0; mi < 2; mi++)
#pragma unroll
    for (int j = 0; j < 4; j++) {
      int r = mi * 16 + hi * 4 + j;
      float ss = 0.f, qq = 0.f;
#pragma unroll
      for (int ww = 0; ww < 8; ww++) { ss += rsum[ww][r]; qq += rsq[ww][r]; }
      mu[mi][j] = ss * (1.0f / 1024.0f);
      float var = qq * (1.0f / 1024.0f) - mu[mi][j] * mu[mi][j];
      rstd[mi][j] = rsqrtf(var + 1e-5f);
    }
#pragma unroll
  for (int mi = 0; mi < 2; mi++) {
#pragma unroll
    for (int ni = 0; ni < 8; ni++) {
      int col = w * 128 + ni * 16 + rl;
      float g = gamma[col], be = beta[col];
#pragma unroll
      for (int j = 0; j < 4; j++) {
        int r = mi * 16 + hi * 4 + j;
        out[(long)(m0 + r) * 1024 + col] = (acc[mi][ni][j] - mu[mi][j]) * rstd[mi][j] * g + be;
      }
    }
  }
}

// ---------------- fused scores+mask+softmax+attnwrite+PV, K/V L2-direct
// 8-wave (512-thr) variant: wave w owns 128 k-cols in QK (acc[8]); PV split
// (d-tile = w&3, k-half = w>>2) with LDS partial combine. 32 waves/CU.
__global__ __launch_bounds__(512) void attn_fused2(
    const unsigned short* __restrict__ Qh, const unsigned short* __restrict__ Kh,
    const unsigned short* __restrict__ Vt, const unsigned* __restrict__ mb,
    float* __restrict__ attn, unsigned short* __restrict__ ctx) {
  const int lin = blockIdx.x;
  const int xcd = lin & 7;
  const int k_ = lin >> 3;
  const int z = xcd + ((k_ >> 3) << 3);  // z % 8 == xcd
  const int qt = k_ & 7;
  const int b = z >> 4, h = z & 15;
  const int tid = threadIdx.x, l = tid & 63, w = tid >> 6;  // w in 0..7
  const int rl = l & 15, hi = l >> 4;

  __shared__ __attribute__((aligned(16))) unsigned short Pl[16 * 1024];  // 32 KB swz
  __shared__ float redm[8][16], reds[8][16];
  __shared__ __attribute__((aligned(16))) float Pp[4][64][4];  // 4 KB partials

  const long bh = (long)z * (SLEN * DKH);
  const unsigned short* Kb = Kh + bh;
  const unsigned short* Vb = Vt + bh;
  const long abase = (long)z << 20;

  bf16x8 qf0, qf1;
  {
    const unsigned short* qp = Qh + bh + (long)(qt * 128 + rl) * 64 + hi * 8;
    qf0 = *(const bf16x8*)qp;
    qf1 = *(const bf16x8*)(qp + 32);
  }

  for (int s = 0; s < 8; s++) {
    const int q0 = qt * 128 + s * 16;

    f32x4 acc[8];
#pragma unroll
    for (int t = 0; t < 8; t++) acc[t] = f32x4{0.f, 0.f, 0.f, 0.f};

    __builtin_amdgcn_s_setprio(1);
#pragma unroll
    for (int t = 0; t < 8; t++) {
      int col = w * 128 + t * 16 + rl;
      const unsigned short* kp = Kb + (long)col * 64 + hi * 8;
      bf16x8 k0 = *(const bf16x8*)kp;
      bf16x8 k1 = *(const bf16x8*)(kp + 32);
      acc[t] = __builtin_amdgcn_mfma_f32_16x16x32_bf16(k0, qf0, acc[t], 0, 0, 0);
      acc[t] = __builtin_amdgcn_mfma_f32_16x16x32_bf16(k1, qf1, acc[t], 0, 0, 0);
    }
    __builtin_amdgcn_s_setprio(0);

    unsigned mw[4];
    {
      uint4 w0 = *(const uint4*)(mb + (((long)((b << 10) | (q0 + rl))) << 5) + w * 4);
      mw[0] = w0.x; mw[1] = w0.y; mw[2] = w0.z; mw[3] = w0.w;
    }

    float mx = -3.0e38f;
#pragma unroll
    for (int t = 0; t < 8; t++) {
#pragma unroll
      for (int j = 0; j < 4; j++) {
        unsigned bit = (mw[t >> 1] >> (((t & 1) << 4) + (hi << 2) + j)) & 1u;
        float v = bit ? -1.0e9f : acc[t][j];
        acc[t][j] = v;
        mx = fmaxf(mx, v);
      }
    }
    mx = fmaxf(mx, __shfl_xor(mx, 16));
    mx = fmaxf(mx, __shfl_xor(mx, 32));
    float sum = 0.f;
#pragma unroll
    for (int t = 0; t < 8; t++)
#pragma unroll
      for (int j = 0; j < 4; j++) {
        float e = __expf(acc[t][j] - mx);
        acc[t][j] = e;
        sum += e;
      }
    sum += __shfl_xor(sum, 16);
    sum += __shfl_xor(sum, 32);
    if (hi == 0) { redm[w][rl] = mx; reds[w][rl] = sum; }
    __syncthreads();  // BARRIER1
    float M, S, inv;
    {
      M = -3.0e38f;
#pragma unroll
      for (int ww = 0; ww < 8; ww++) M = fmaxf(M, redm[ww][rl]);
      S = 0.f;
#pragma unroll
      for (int ww = 0; ww < 8; ww++) S += reds[ww][rl] * __expf(redm[ww][rl] - M);
      inv = __expf(mx - M) / S;
    }

#pragma unroll
    for (int t = 0; t < 8; t++) {
      int c0 = w * 128 + t * 16 + hi * 4;
      union { unsigned short us[4]; unsigned long long v; } pk;
      pk.us[0] = f2bf(acc[t][0] * inv);
      pk.us[1] = f2bf(acc[t][1] * inv);
      pk.us[2] = f2bf(acc[t][2] * inv);
      pk.us[3] = f2bf(acc[t][3] * inv);
      *(unsigned long long*)((char*)Pl + rl * 2048 + ((c0 * 2) ^ ((rl & 7) << 4))) = pk.v;
    }
    __syncthreads();  // BARRIER2

    {
      const int half = tid >> 8;
      const int t8 = tid & 255;
      const long arow = abase + ((long)q0 << 10) + t8 * 4;
#pragma unroll
      for (int i = 0; i < 8; i++) {
        int row = i * 2 + half;
        unsigned long long pv8 = *(const unsigned long long*)(
            (const char*)Pl + row * 2048 + ((t8 * 8) ^ ((row & 7) << 4)));
        f32x4 o4;
        o4[0] = __builtin_bit_cast(float, (unsigned)((pv8 & 0xFFFFu) << 16));
        o4[1] = __builtin_bit_cast(float, (unsigned)(((pv8 >> 16) & 0xFFFFu) << 16));
        o4[2] = __builtin_bit_cast(float, (unsigned)(((pv8 >> 32) & 0xFFFFu) << 16));
        o4[3] = __builtin_bit_cast(float, (unsigned)(((pv8 >> 48) & 0xFFFFu) << 16));
        __builtin_nontemporal_store(o4, (f32x4*)&attn[arow + ((long)row << 10)]);
      }
    }

    if (s < 7) {
      const unsigned short* qp = Qh + bh + (long)(q0 + 16 + rl) * 64 + hi * 8;
      qf0 = *(const bf16x8*)qp;
      qf1 = *(const bf16x8*)(qp + 32);
    }

    const int d4 = w & 3, kh = w >> 2;
    f32x4 c2 = f32x4{0.f, 0.f, 0.f, 0.f};
    __builtin_amdgcn_s_setprio(1);
#pragma unroll
    for (int k16 = 0; k16 < 16; k16++) {
      int ks = kh * 16 + k16;
      bf16x8 af = *(const bf16x8*)((const char*)Pl + rl * 2048 + ((ks * 64 + hi * 16) ^ ((rl & 7) << 4)));
      bf16x8 vf = *(const bf16x8*)(Vb + (long)(d4 * 16 + rl) * 1024 + ks * 32 + hi * 8);
      c2 = __builtin_amdgcn_mfma_f32_16x16x32_bf16(af, vf, c2, 0, 0, 0);
    }
    __builtin_amdgcn_s_setprio(0);

    if (w < 4) {
      *(f32x4*)Pp[w][l] = c2;
    }
    __syncthreads();  // BARRIER3
    if (w >= 4) {
      f32x4 p = *(const f32x4*)Pp[w - 4][l];
#pragma unroll
      for (int j = 0; j < 4; j++) {
        __builtin_nontemporal_store(
            f2bf(c2[j] + p[j]),
            &ctx[((long)(b * 1024 + q0 + hi * 4 + j) << 10) + h * 64 + d4 * 16 + rl]);
      }
    }
  }
}

extern "C" void kernel_launch(void* const* d_in, const int* in_sizes, int n_in,
                              void* d_out, int out_size, void* d_ws, size_t ws_size,
                              hipStream_t stream) {
  const float* inQ = (const float*)d_in[0];
  const float* inK = (const float*)d_in[1];
  const float* inV = (const float*)d_in[2];
  const unsigned char* mask = (const unsigned char*)d_in[3];
  const float* WQ = (const float*)d_in[4];
  const float* WK = (const float*)d_in[5];
  const float* WV = (const float*)d_in[6];
  const float* WFC = (const float*)d_in[7];
  const float* gamma = (const float*)d_in[8];
  const float* beta = (const float*)d_in[9];

  float* out = (float*)d_out;
  float* attn = out + (size_t)BATCH * SLEN * DMODEL;

  char* ws = (char*)d_ws;
  size_t off = 256;
  int* flag = (int*)ws;
  auto take = [&](size_t bytes) { char* p = ws + off; off += (bytes + 255) & ~255UL; return p; };
  const size_t XB = (size_t)BATCH * SLEN * DMODEL * 2;
  const size_t WB = (size_t)DMODEL * DMODEL * 2;
  unsigned short* Xq = (unsigned short*)take(XB);
  unsigned short* Xk = (unsigned short*)take(XB);
  unsigned short* Xv = (unsigned short*)take(XB);
  unsigned short* Wqb = (unsigned short*)take(WB);
  unsigned short* Wkb = (unsigned short*)take(WB);
  unsigned short* Wvb = (unsigned short*)take(WB);
  unsigned short* Wfcb = (unsigned short*)take(WB);
  unsigned short* Qh = (unsigned short*)take(XB);
  unsigned short* Kh = (unsigned short*)take(XB);
  unsigned short* Vt = (unsigned short*)take(XB);
  unsigned short* ctx = (unsigned short*)take(XB);
  unsigned* mb = (unsigned*)take((size_t)BATCH * SLEN * 32 * 4);  // 1 MB bitmask

  detect_mask<<<1, 64, 0, stream>>>(mask, flag);
  mask_pack<<<BATCH * SLEN, 256, 0, stream>>>(mask, flag, mb);

  const int n8x = BATCH * SLEN * DMODEL / 8;
  const int n8w = DMODEL * DMODEL / 8;
  cvt_all<<<dim3(n8x / 256, 7), 256, 0, stream>>>(inQ, inK, inV, WQ, WK, WV, WFC,
                                                  Xq, Xk, Xv, Wqb, Wkb, Wvb, Wfcb,
                                                  n8x, n8w);

  gemm_proj3<<<dim3(64, 8, 3), 256, 0, stream>>>(Xq, Xk, Xv, Wqb, Wkb, Wvb, Qh, Kh, Vt);

  attn_fused2<<<dim3(1024), 512, 0, stream>>>(Qh, Kh, Vt, mb, attn, ctx);

  gemm_fc_ln<<<dim3(256), 512, 0, stream>>>(ctx, Wfcb, inQ, gamma, beta, out);
}

// Round 20
// 305.826 us; speedup vs baseline: 1.1440x; 1.1440x over previous
//
#include <hip/hip_runtime.h>

typedef __attribute__((ext_vector_type(8))) __bf16 bf16x8;
typedef __attribute__((ext_vector_type(4))) float f32x4;

#define SLEN 1024
#define DMODEL 1024
#define NHEADS 16
#define DKH 64
#define BATCH 8

__device__ __forceinline__ unsigned short f2bf(float f) {
  unsigned u = __builtin_bit_cast(unsigned, f);
  u += 0x7FFFu + ((u >> 16) & 1u);
  return (unsigned short)(u >> 16);
}

__device__ __forceinline__ void gload_lds16(const void* g, void* l) {
  __builtin_amdgcn_global_load_lds((const __attribute__((address_space(1))) unsigned int*)g,
                                   (__attribute__((address_space(3))) unsigned int*)l, 16, 0, 0);
}

// ---------------- mask dtype detection: flag=1 -> byte mask, 0 -> int32 mask
__global__ void detect_mask(const unsigned char* __restrict__ m, int* __restrict__ flag) {
  int t = threadIdx.x;
  unsigned any = 0;
  for (int j = t; j < 4096; j += 64) any |= m[j * 4 + 1];
  unsigned long long b = __ballot(any != 0);
  if (t == 0) *flag = (b != 0) ? 1 : 0;
}

// ---------------- bit-pack mask: one block per (b,q) row of 1024 -> 32 words
__global__ __launch_bounds__(256) void mask_pack(const unsigned char* __restrict__ m,
                                                 const int* __restrict__ flagp,
                                                 unsigned* __restrict__ mb) {
  long base = (long)blockIdx.x << 10;
  int tid = threadIdx.x;
  int flag = *flagp;
  unsigned nib;
  if (flag) {
    uchar4 v = ((const uchar4*)(m + base))[tid];
    nib = (v.x ? 1u : 0u) | (v.y ? 2u : 0u) | (v.z ? 4u : 0u) | (v.w ? 8u : 0u);
  } else {
    int4 v = ((const int4*)((const int*)m + base))[tid];
    nib = (v.x ? 1u : 0u) | (v.y ? 2u : 0u) | (v.z ? 4u : 0u) | (v.w ? 8u : 0u);
  }
  __shared__ unsigned char nibs[256];
  nibs[tid] = (unsigned char)nib;
  __syncthreads();
  if (tid < 32) {
    unsigned wv = 0;
#pragma unroll
    for (int i = 0; i < 8; i++) wv |= ((unsigned)nibs[tid * 8 + i]) << (i * 4);
    mb[((long)blockIdx.x << 5) + tid] = wv;
  }
}

// ---------------- fp32 -> bf16 bulk convert, 7 tensors via blockIdx.y
__global__ __launch_bounds__(256) void cvt_all(
    const float* __restrict__ i0, const float* __restrict__ i1,
    const float* __restrict__ i2, const float* __restrict__ w0,
    const float* __restrict__ w1, const float* __restrict__ w2,
    const float* __restrict__ w3, unsigned short* __restrict__ xo0,
    unsigned short* __restrict__ xo1, unsigned short* __restrict__ xo2,
    unsigned short* __restrict__ wo0, unsigned short* __restrict__ wo1,
    unsigned short* __restrict__ wo2, unsigned short* __restrict__ wo3,
    int n8x, int n8w) {
  int which = blockIdx.y;
  const float* in;
  unsigned short* o;
  int n8;
  if (which < 3) {
    in = which == 0 ? i0 : which == 1 ? i1 : i2;
    o = which == 0 ? xo0 : which == 1 ? xo1 : xo2;
    n8 = n8x;
  } else {
    in = which == 3 ? w0 : which == 4 ? w1 : which == 5 ? w2 : w3;
    o = which == 3 ? wo0 : which == 4 ? wo1 : which == 5 ? wo2 : wo3;
    n8 = n8w;
  }
  int i = blockIdx.x * 256 + threadIdx.x;
  if (i >= n8) return;
  const float4* p = (const float4*)in;
  float4 f0 = p[2 * i], f1 = p[2 * i + 1];
  union { unsigned short us[8]; uint4 v; } pk;
  pk.us[0] = f2bf(f0.x); pk.us[1] = f2bf(f0.y); pk.us[2] = f2bf(f0.z); pk.us[3] = f2bf(f0.w);
  pk.us[4] = f2bf(f1.x); pk.us[5] = f2bf(f1.y); pk.us[6] = f2bf(f1.z); pk.us[7] = f2bf(f1.w);
  ((uint4*)o)[i] = pk.v;
}

// ---------------- merged QKV projection GEMM (z = 0/1/2 -> Q/K/V)
// bf16 NT, BK=64, XOR-swizzled LDS; z==2 writes V TRANSPOSED [z][d][s] (b64)
__global__ __launch_bounds__(256) void gemm_proj3(
    const unsigned short* __restrict__ A0, const unsigned short* __restrict__ A1,
    const unsigned short* __restrict__ A2, const unsigned short* __restrict__ B0,
    const unsigned short* __restrict__ B1, const unsigned short* __restrict__ B2,
    unsigned short* __restrict__ O0, unsigned short* __restrict__ O1,
    unsigned short* __restrict__ O2) {
  const int z = blockIdx.z;
  const unsigned short* Ab = z == 0 ? A0 : z == 1 ? A1 : A2;
  const unsigned short* Bb = z == 0 ? B0 : z == 1 ? B1 : B2;
  unsigned short* obf = z == 0 ? O0 : z == 1 ? O1 : O2;
  const float scale = z == 0 ? 0.125f : 1.0f;

  const int m0 = blockIdx.x * 128;
  const int n0 = blockIdx.y * 128;
  const int tid = threadIdx.x;
  const int l = tid & 63;
  const int w = tid >> 6;
  const int wr = w >> 1, wc = w & 1;
  const int rl = l & 15, hi = l >> 4;

  __shared__ __attribute__((aligned(16))) unsigned short As[128 * 64];
  __shared__ __attribute__((aligned(16))) unsigned short Bs[128 * 64];

  f32x4 acc[4][4];
#pragma unroll
  for (int i = 0; i < 4; i++)
#pragma unroll
    for (int j = 0; j < 4; j++) acc[i][j] = f32x4{0.f, 0.f, 0.f, 0.f};

  for (int k0 = 0; k0 < 1024; k0 += 64) {
    __syncthreads();
#pragma unroll
    for (int i = 0; i < 4; i++) {
      int o = (i * 256 + tid) * 16;
      int row = o >> 7, cb = o & 127;
      int cbs = cb ^ ((row & 7) << 4);
      gload_lds16(Ab + (long)(m0 + row) * 1024 + k0 + (cbs >> 1), (char*)As + o);
    }
#pragma unroll
    for (int i = 0; i < 4; i++) {
      int o = (i * 256 + tid) * 16;
      int row = o >> 7, cb = o & 127;
      int cbs = cb ^ ((row & 7) << 4);
      gload_lds16(Bb + (long)(n0 + row) * 1024 + k0 + (cbs >> 1), (char*)Bs + o);
    }
    __syncthreads();

#pragma unroll
    for (int ks = 0; ks < 2; ks++) {
      int kb = ks * 64 + hi * 16;
      bf16x8 af[4], bfr[4];
#pragma unroll
      for (int mi = 0; mi < 4; mi++) {
        int row = wr * 64 + mi * 16 + rl;
        af[mi] = *(const bf16x8*)((const char*)As + row * 128 + (kb ^ ((row & 7) << 4)));
      }
#pragma unroll
      for (int ni = 0; ni < 4; ni++) {
        int row = wc * 64 + ni * 16 + rl;
        bfr[ni] = *(const bf16x8*)((const char*)Bs + row * 128 + (kb ^ ((row & 7) << 4)));
      }
#pragma unroll
      for (int mi = 0; mi < 4; mi++)
#pragma unroll
        for (int ni = 0; ni < 4; ni++)
          acc[mi][ni] = __builtin_amdgcn_mfma_f32_16x16x32_bf16(af[mi], bfr[ni], acc[mi][ni], 0, 0, 0);
    }
  }

  const int r0 = hi << 2;
#pragma unroll
  for (int mi = 0; mi < 4; mi++) {
#pragma unroll
    for (int ni = 0; ni < 4; ni++) {
      f32x4 v = acc[mi][ni];
      int row = m0 + wr * 64 + mi * 16 + r0;
      int col = n0 + wc * 64 + ni * 16 + rl;
      if (z == 2) {
        union { unsigned short us[4]; unsigned long long vv; } pk;
        pk.us[0] = f2bf(v[0]); pk.us[1] = f2bf(v[1]);
        pk.us[2] = f2bf(v[2]); pk.us[3] = f2bf(v[3]);
        long idx = ((long)(((row >> 10) * 16 + (col >> 6)) * 64 + (col & 63)) << 10) + (row & 1023);
        *(unsigned long long*)&obf[idx] = pk.vv;
      } else {
#pragma unroll
        for (int j = 0; j < 4; j++) {
          int rr = row + j;
          long idx = (((long)((rr >> 10) * 16 + (col >> 6)) * 1024 + (rr & 1023)) << 6) + (col & 63);
          obf[idx] = f2bf(v[j] * scale);
        }
      }
    }
  }
}

// ---------------- FC GEMM: fp32 out row-major, BK=64 + swizzle
__global__ __launch_bounds__(256) void gemm_fc(
    const unsigned short* __restrict__ Ab, const unsigned short* __restrict__ Bb,
    float* __restrict__ of32) {
  const int m0 = blockIdx.x * 128;
  const int n0 = blockIdx.y * 128;
  const int tid = threadIdx.x;
  const int l = tid & 63;
  const int w = tid >> 6;
  const int wr = w >> 1, wc = w & 1;
  const int rl = l & 15, hi = l >> 4;

  __shared__ __attribute__((aligned(16))) unsigned short As[128 * 64];
  __shared__ __attribute__((aligned(16))) unsigned short Bs[128 * 64];

  f32x4 acc[4][4];
#pragma unroll
  for (int i = 0; i < 4; i++)
#pragma unroll
    for (int j = 0; j < 4; j++) acc[i][j] = f32x4{0.f, 0.f, 0.f, 0.f};

  for (int k0 = 0; k0 < 1024; k0 += 64) {
    __syncthreads();
#pragma unroll
    for (int i = 0; i < 4; i++) {
      int o = (i * 256 + tid) * 16;
      int row = o >> 7, cb = o & 127;
      int cbs = cb ^ ((row & 7) << 4);
      gload_lds16(Ab + (long)(m0 + row) * 1024 + k0 + (cbs >> 1), (char*)As + o);
    }
#pragma unroll
    for (int i = 0; i < 4; i++) {
      int o = (i * 256 + tid) * 16;
      int row = o >> 7, cb = o & 127;
      int cbs = cb ^ ((row & 7) << 4);
      gload_lds16(Bb + (long)(n0 + row) * 1024 + k0 + (cbs >> 1), (char*)Bs + o);
    }
    __syncthreads();

#pragma unroll
    for (int ks = 0; ks < 2; ks++) {
      int kb = ks * 64 + hi * 16;
      bf16x8 af[4], bfr[4];
#pragma unroll
      for (int mi = 0; mi < 4; mi++) {
        int row = wr * 64 + mi * 16 + rl;
        af[mi] = *(const bf16x8*)((const char*)As + row * 128 + (kb ^ ((row & 7) << 4)));
      }
#pragma unroll
      for (int ni = 0; ni < 4; ni++) {
        int row = wc * 64 + ni * 16 + rl;
        bfr[ni] = *(const bf16x8*)((const char*)Bs + row * 128 + (kb ^ ((row & 7) << 4)));
      }
#pragma unroll
      for (int mi = 0; mi < 4; mi++)
#pragma unroll
        for (int ni = 0; ni < 4; ni++)
          acc[mi][ni] = __builtin_amdgcn_mfma_f32_16x16x32_bf16(af[mi], bfr[ni], acc[mi][ni], 0, 0, 0);
    }
  }

  const int r0 = hi << 2;
#pragma unroll
  for (int mi = 0; mi < 4; mi++) {
#pragma unroll
    for (int ni = 0; ni < 4; ni++) {
      f32x4 v = acc[mi][ni];
      int row = m0 + wr * 64 + mi * 16 + r0;
      int col = n0 + wc * 64 + ni * 16 + rl;
#pragma unroll
      for (int j = 0; j < 4; j++)
        of32[((long)(row + j) << 10) + col] = v[j];
    }
  }
}

// ---------------- fused scores+mask+softmax+attnwrite+PV, K/V L2-direct
// 8-wave (512-thr): wave w owns 128 k-cols in QK (acc[8]); PV split
// (d-tile = w&3, k-half = w>>2) with LDS partial combine. 32 waves/CU.
__global__ __launch_bounds__(512) void attn_fused2(
    const unsigned short* __restrict__ Qh, const unsigned short* __restrict__ Kh,
    const unsigned short* __restrict__ Vt, const unsigned* __restrict__ mb,
    float* __restrict__ attn, unsigned short* __restrict__ ctx) {
  const int lin = blockIdx.x;
  const int xcd = lin & 7;
  const int k_ = lin >> 3;
  const int z = xcd + ((k_ >> 3) << 3);  // z % 8 == xcd
  const int qt = k_ & 7;
  const int b = z >> 4, h = z & 15;
  const int tid = threadIdx.x, l = tid & 63, w = tid >> 6;  // w in 0..7
  const int rl = l & 15, hi = l >> 4;

  __shared__ __attribute__((aligned(16))) unsigned short Pl[16 * 1024];  // 32 KB swz
  __shared__ float redm[8][16], reds[8][16];
  __shared__ __attribute__((aligned(16))) float Pp[4][64][4];  // 4 KB partials

  const long bh = (long)z * (SLEN * DKH);
  const unsigned short* Kb = Kh + bh;
  const unsigned short* Vb = Vt + bh;
  const long abase = (long)z << 20;

  bf16x8 qf0, qf1;
  {
    const unsigned short* qp = Qh + bh + (long)(qt * 128 + rl) * 64 + hi * 8;
    qf0 = *(const bf16x8*)qp;
    qf1 = *(const bf16x8*)(qp + 32);
  }

  for (int s = 0; s < 8; s++) {
    const int q0 = qt * 128 + s * 16;

    f32x4 acc[8];
#pragma unroll
    for (int t = 0; t < 8; t++) acc[t] = f32x4{0.f, 0.f, 0.f, 0.f};

    __builtin_amdgcn_s_setprio(1);
#pragma unroll
    for (int t = 0; t < 8; t++) {
      int col = w * 128 + t * 16 + rl;
      const unsigned short* kp = Kb + (long)col * 64 + hi * 8;
      bf16x8 k0 = *(const bf16x8*)kp;
      bf16x8 k1 = *(const bf16x8*)(kp + 32);
      acc[t] = __builtin_amdgcn_mfma_f32_16x16x32_bf16(k0, qf0, acc[t], 0, 0, 0);
      acc[t] = __builtin_amdgcn_mfma_f32_16x16x32_bf16(k1, qf1, acc[t], 0, 0, 0);
    }
    __builtin_amdgcn_s_setprio(0);

    unsigned mw[4];
    {
      uint4 w0 = *(const uint4*)(mb + (((long)((b << 10) | (q0 + rl))) << 5) + w * 4);
      mw[0] = w0.x; mw[1] = w0.y; mw[2] = w0.z; mw[3] = w0.w;
    }

    float mx = -3.0e38f;
#pragma unroll
    for (int t = 0; t < 8; t++) {
#pragma unroll
      for (int j = 0; j < 4; j++) {
        unsigned bit = (mw[t >> 1] >> (((t & 1) << 4) + (hi << 2) + j)) & 1u;
        float v = bit ? -1.0e9f : acc[t][j];
        acc[t][j] = v;
        mx = fmaxf(mx, v);
      }
    }
    mx = fmaxf(mx, __shfl_xor(mx, 16));
    mx = fmaxf(mx, __shfl_xor(mx, 32));
    float sum = 0.f;
#pragma unroll
    for (int t = 0; t < 8; t++)
#pragma unroll
      for (int j = 0; j < 4; j++) {
        float e = __expf(acc[t][j] - mx);
        acc[t][j] = e;
        sum += e;
      }
    sum += __shfl_xor(sum, 16);
    sum += __shfl_xor(sum, 32);
    if (hi == 0) { redm[w][rl] = mx; reds[w][rl] = sum; }
    __syncthreads();  // BARRIER1
    float M, S, inv;
    {
      M = -3.0e38f;
#pragma unroll
      for (int ww = 0; ww < 8; ww++) M = fmaxf(M, redm[ww][rl]);
      S = 0.f;
#pragma unroll
      for (int ww = 0; ww < 8; ww++) S += reds[ww][rl] * __expf(redm[ww][rl] - M);
      inv = __expf(mx - M) / S;
    }

#pragma unroll
    for (int t = 0; t < 8; t++) {
      int c0 = w * 128 + t * 16 + hi * 4;
      union { unsigned short us[4]; unsigned long long v; } pk;
      pk.us[0] = f2bf(acc[t][0] * inv);
      pk.us[1] = f2bf(acc[t][1] * inv);
      pk.us[2] = f2bf(acc[t][2] * inv);
      pk.us[3] = f2bf(acc[t][3] * inv);
      *(unsigned long long*)((char*)Pl + rl * 2048 + ((c0 * 2) ^ ((rl & 7) << 4))) = pk.v;
    }
    __syncthreads();  // BARRIER2

    {
      const int half = tid >> 8;
      const int t8 = tid & 255;
      const long arow = abase + ((long)q0 << 10) + t8 * 4;
#pragma unroll
      for (int i = 0; i < 8; i++) {
        int row = i * 2 + half;
        unsigned long long pv8 = *(const unsigned long long*)(
            (const char*)Pl + row * 2048 + ((t8 * 8) ^ ((row & 7) << 4)));
        f32x4 o4;
        o4[0] = __builtin_bit_cast(float, (unsigned)((pv8 & 0xFFFFu) << 16));
        o4[1] = __builtin_bit_cast(float, (unsigned)(((pv8 >> 16) & 0xFFFFu) << 16));
        o4[2] = __builtin_bit_cast(float, (unsigned)(((pv8 >> 32) & 0xFFFFu) << 16));
        o4[3] = __builtin_bit_cast(float, (unsigned)(((pv8 >> 48) & 0xFFFFu) << 16));
        __builtin_nontemporal_store(o4, (f32x4*)&attn[arow + ((long)row << 10)]);
      }
    }

    if (s < 7) {
      const unsigned short* qp = Qh + bh + (long)(q0 + 16 + rl) * 64 + hi * 8;
      qf0 = *(const bf16x8*)qp;
      qf1 = *(const bf16x8*)(qp + 32);
    }

    const int d4 = w & 3, kh = w >> 2;
    f32x4 c2 = f32x4{0.f, 0.f, 0.f, 0.f};
    __builtin_amdgcn_s_setprio(1);
#pragma unroll
    for (int k16 = 0; k16 < 16; k16++) {
      int ks = kh * 16 + k16;
      bf16x8 af = *(const bf16x8*)((const char*)Pl + rl * 2048 + ((ks * 64 + hi * 16) ^ ((rl & 7) << 4)));
      bf16x8 vf = *(const bf16x8*)(Vb + (long)(d4 * 16 + rl) * 1024 + ks * 32 + hi * 8);
      c2 = __builtin_amdgcn_mfma_f32_16x16x32_bf16(af, vf, c2, 0, 0, 0);
    }
    __builtin_amdgcn_s_setprio(0);

    if (w < 4) {
      *(f32x4*)Pp[w][l] = c2;
    }
    __syncthreads();  // BARRIER3
    if (w >= 4) {
      f32x4 p = *(const f32x4*)Pp[w - 4][l];
#pragma unroll
      for (int j = 0; j < 4; j++) {
        __builtin_nontemporal_store(
            f2bf(c2[j] + p[j]),
            &ctx[((long)(b * 1024 + q0 + hi * 4 + j) << 10) + h * 64 + d4 * 16 + rl]);
      }
    }
  }
}

// ---------------- residual + LayerNorm, one block per row
__global__ __launch_bounds__(256) void ln_kernel(const float* __restrict__ fc,
                                                 const float* __restrict__ inQ,
                                                 const float* __restrict__ gamma,
                                                 const float* __restrict__ beta,
                                                 float* __restrict__ out) {
  long base = (long)blockIdx.x << 10;
  int tid = threadIdx.x, l = tid & 63, w = tid >> 6;
  float4 a = ((const float4*)(fc + base))[tid];
  float4 b = ((const float4*)(inQ + base))[tid];
  float4 x; x.x = a.x + b.x; x.y = a.y + b.y; x.z = a.z + b.z; x.w = a.w + b.w;
  float s = x.x + x.y + x.z + x.w;
  float q = x.x * x.x + x.y * x.y + x.z * x.z + x.w * x.w;
  for (int o = 32; o; o >>= 1) { s += __shfl_xor(s, o); q += __shfl_xor(q, o); }
  __shared__ float rs[4], rq[4];
  if (l == 0) { rs[w] = s; rq[w] = q; }
  __syncthreads();
  s = rs[0] + rs[1] + rs[2] + rs[3];
  q = rq[0] + rq[1] + rq[2] + rq[3];
  float mu = s * (1.0f / 1024.0f);
  float var = q * (1.0f / 1024.0f) - mu * mu;
  float rstd = rsqrtf(var + 1e-5f);
  float4 g = ((const float4*)gamma)[tid];
  float4 be = ((const float4*)beta)[tid];
  float4 o4;
  o4.x = (x.x - mu) * rstd * g.x + be.x;
  o4.y = (x.y - mu) * rstd * g.y + be.y;
  o4.z = (x.z - mu) * rstd * g.z + be.z;
  o4.w = (x.w - mu) * rstd * g.w + be.w;
  ((float4*)(out + base))[tid] = o4;
}

extern "C" void kernel_launch(void* const* d_in, const int* in_sizes, int n_in,
                              void* d_out, int out_size, void* d_ws, size_t ws_size,
                              hipStream_t stream) {
  const float* inQ = (const float*)d_in[0];
  const float* inK = (const float*)d_in[1];
  const float* inV = (const float*)d_in[2];
  const unsigned char* mask = (const unsigned char*)d_in[3];
  const float* WQ = (const float*)d_in[4];
  const float* WK = (const float*)d_in[5];
  const float* WV = (const float*)d_in[6];
  const float* WFC = (const float*)d_in[7];
  const float* gamma = (const float*)d_in[8];
  const float* beta = (const float*)d_in[9];

  float* out = (float*)d_out;
  float* attn = out + (size_t)BATCH * SLEN * DMODEL;

  char* ws = (char*)d_ws;
  size_t off = 256;
  int* flag = (int*)ws;
  auto take = [&](size_t bytes) { char* p = ws + off; off += (bytes + 255) & ~255UL; return p; };
  const size_t XB = (size_t)BATCH * SLEN * DMODEL * 2;
  const size_t WB = (size_t)DMODEL * DMODEL * 2;
  unsigned short* Xq = (unsigned short*)take(XB);
  unsigned short* Xk = (unsigned short*)take(XB);
  unsigned short* Xv = (unsigned short*)take(XB);
  unsigned short* Wqb = (unsigned short*)take(WB);
  unsigned short* Wkb = (unsigned short*)take(WB);
  unsigned short* Wvb = (unsigned short*)take(WB);
  unsigned short* Wfcb = (unsigned short*)take(WB);
  unsigned short* Qh = (unsigned short*)take(XB);
  unsigned short* Kh = (unsigned short*)take(XB);
  unsigned short* Vt = (unsigned short*)take(XB);
  unsigned short* ctx = (unsigned short*)take(XB);
  float* fc = (float*)take((size_t)BATCH * SLEN * DMODEL * 4);
  unsigned* mb = (unsigned*)take((size_t)BATCH * SLEN * 32 * 4);  // 1 MB bitmask

  detect_mask<<<1, 64, 0, stream>>>(mask, flag);
  mask_pack<<<BATCH * SLEN, 256, 0, stream>>>(mask, flag, mb);

  const int n8x = BATCH * SLEN * DMODEL / 8;
  const int n8w = DMODEL * DMODEL / 8;
  cvt_all<<<dim3(n8x / 256, 7), 256, 0, stream>>>(inQ, inK, inV, WQ, WK, WV, WFC,
                                                  Xq, Xk, Xv, Wqb, Wkb, Wvb, Wfcb,
                                                  n8x, n8w);

  gemm_proj3<<<dim3(64, 8, 3), 256, 0, stream>>>(Xq, Xk, Xv, Wqb, Wkb, Wvb, Qh, Kh, Vt);

  attn_fused2<<<dim3(1024), 512, 0, stream>>>(Qh, Kh, Vt, mb, attn, ctx);

  gemm_fc<<<dim3(64, 8), 256, 0, stream>>>(ctx, Wfcb, fc);

  ln_kernel<<<BATCH * SLEN, 256, 0, stream>>>(fc, inQ, gamma, beta, out);
}